// Round 2
// baseline (105.965 us; speedup 1.0000x reference)
//
#include <hip/hip_runtime.h>

#define NS 1024
#define KD 256   // x_dim == y_dim
#define H  256

// ---------------------------------------------------------------------------
// proj_kernel: PX = X @ W1[:KD], PYB = Y @ W1[KD:] + b1
// grid (H/64=4, NS/32=32, 2), block 256. z=0 -> PX, z=1 -> PYB.
// ---------------------------------------------------------------------------
__global__ __launch_bounds__(256) void proj_kernel(
    const float* __restrict__ X, const float* __restrict__ Y,
    const float* __restrict__ W1, const float* __restrict__ b1,
    float* __restrict__ PX, float* __restrict__ PYB)
{
    const int z = blockIdx.z;
    const float* __restrict__ A = z ? Y : X;
    const float* __restrict__ W = W1 + (z ? KD * H : 0);
    float* __restrict__ OUT = z ? PYB : PX;

    __shared__ float xs[32][36];   // transposed [k][i], pad to 36 (bank spread)
    __shared__ float ws[32][64];   // [k][h]

    const int tid = threadIdx.x;
    const int tx = tid & 15;       // h direction (x4)
    const int ty = tid >> 4;       // i direction (x2), 0..15
    const int i0 = blockIdx.y * 32, h0 = blockIdx.x * 64;

    float acc[2][4] = {};

    for (int k0 = 0; k0 < KD; k0 += 32) {
        // stage W tile [32][64], coalesced (h contiguous)
        #pragma unroll
        for (int s = 0; s < 8; ++s) {
            int f = tid + 256 * s;
            int kk = f >> 6, hh = f & 63;
            ws[kk][hh] = W[(k0 + kk) * H + h0 + hh];
        }
        // stage A tile transposed: lane owns row ii, reads float4 along k
        {
            int ii = tid & 31, q = tid >> 5;   // q = 0..7
            float4 v = *(const float4*)&A[(i0 + ii) * KD + k0 + q * 4];
            xs[q * 4 + 0][ii] = v.x;
            xs[q * 4 + 1][ii] = v.y;
            xs[q * 4 + 2][ii] = v.z;
            xs[q * 4 + 3][ii] = v.w;
        }
        __syncthreads();

        #pragma unroll
        for (int kk = 0; kk < 32; ++kk) {
            float xr[2];
            xr[0] = xs[kk][ty * 2 + 0];
            xr[1] = xs[kk][ty * 2 + 1];
            float wc[4];
            *(float4*)wc = *(const float4*)&ws[kk][tx * 4];
            #pragma unroll
            for (int r = 0; r < 2; ++r)
                #pragma unroll
                for (int c = 0; c < 4; ++c)
                    acc[r][c] = fmaf(xr[r], wc[c], acc[r][c]);
        }
        __syncthreads();
    }

    #pragma unroll
    for (int r = 0; r < 2; ++r) {
        const int row = i0 + ty * 2 + r;
        float o[4];
        #pragma unroll
        for (int c = 0; c < 4; ++c) o[c] = acc[r][c];
        if (z) {
            float bv[4];
            *(float4*)bv = *(const float4*)&b1[h0 + tx * 4];
            #pragma unroll
            for (int c = 0; c < 4; ++c) o[c] += bv[c];
        }
        *(float4*)&OUT[row * H + h0 + tx * 4] = *(float4*)o;
    }
}

// ---------------------------------------------------------------------------
// pair_kernel: per 32x64 (i,j) tile, t1 = sum_h relu(pyb_i + px_j)*w2 + b2 - 1
// accumulate sum(exp(t1)) and diagonal sum(t1[i,i]+1) into per-block partials.
// grid (16,32) = 512 blocks -> 2 blocks/CU (2 waves/SIMD). block 256
// (16x16 threads, 2 rows x 4 cols per thread).
// ---------------------------------------------------------------------------
__global__ __launch_bounds__(256) void pair_kernel(
    const float* __restrict__ PX, const float* __restrict__ PYB,
    const float* __restrict__ W2, const float* __restrict__ b2,
    float* __restrict__ eparts, float* __restrict__ dparts)
{
    __shared__ float pxt[64][68];  // transposed [h][j], pad 68 (16B-aligned rows)
    __shared__ float pyt[64][36];  // transposed [h][i], 32 rows, pad 36
    __shared__ float w2s[H];
    __shared__ float red_e[256];
    __shared__ float red_d[256];

    const int tid = threadIdx.x;
    const int tx = tid & 15;       // j direction (x4) -> 64 cols
    const int ty = tid >> 4;       // i direction (x2) -> 32 rows
    const int j0 = blockIdx.x * 64, i0 = blockIdx.y * 32;

    w2s[tid] = W2[tid];            // blockDim == H == 256

    const int jrow = tid & 63;     // px staging: lane owns one j-col
    const int jq   = tid >> 6;     // 0..3: 16-wide h quarter
    const int irow = tid & 31;     // py staging: lane owns one i-row
    const int iq   = tid >> 5;     // 0..7: 8-wide h slice

    float acc[2][4] = {};

    for (int h0 = 0; h0 < H; h0 += 64) {
        __syncthreads();   // protect LDS reuse (and w2s on first iter)
        #pragma unroll
        for (int p = 0; p < 4; ++p) {
            const int hh = jq * 16 + p * 4;
            float4 vx = *(const float4*)&PX[(j0 + jrow) * H + h0 + hh];
            pxt[hh + 0][jrow] = vx.x; pxt[hh + 1][jrow] = vx.y;
            pxt[hh + 2][jrow] = vx.z; pxt[hh + 3][jrow] = vx.w;
        }
        #pragma unroll
        for (int p = 0; p < 2; ++p) {
            const int hh = iq * 8 + p * 4;
            float4 vy = *(const float4*)&PYB[(i0 + irow) * H + h0 + hh];
            pyt[hh + 0][irow] = vy.x; pyt[hh + 1][irow] = vy.y;
            pyt[hh + 2][irow] = vy.z; pyt[hh + 3][irow] = vy.w;
        }
        __syncthreads();

        #pragma unroll 4
        for (int hh4 = 0; hh4 < 64; hh4 += 4) {
            float w4[4];
            *(float4*)w4 = *(const float4*)&w2s[h0 + hh4];
            #pragma unroll
            for (int u = 0; u < 4; ++u) {
                const int hh = hh4 + u;
                float py2[2], px4[4];
                *(float2*)py2 = *(const float2*)&pyt[hh][ty * 2];
                *(float4*)px4 = *(const float4*)&pxt[hh][tx * 4];
                #pragma unroll
                for (int r = 0; r < 2; ++r)
                    #pragma unroll
                    for (int c = 0; c < 4; ++c) {
                        float s = py2[r] + px4[c];
                        acc[r][c] = fmaf(fmaxf(s, 0.f), w4[u], acc[r][c]);
                    }
            }
        }
    }

    // epilogue: t1 = acc + (b2 - 1); exp-sum + diagonal t0 contribution
    const float c0 = b2[0] - 1.0f;
    float esum = 0.f, dsum = 0.f;
    #pragma unroll
    for (int r = 0; r < 2; ++r)
        #pragma unroll
        for (int c = 0; c < 4; ++c) {
            const float t1 = acc[r][c] + c0;
            esum += expf(t1);
            if (i0 + ty * 2 + r == j0 + tx * 4 + c) dsum += t1 + 1.0f;
        }

    // merged block tree-reduction (single barrier sequence)
    __syncthreads();
    red_e[tid] = esum;
    red_d[tid] = dsum;
    __syncthreads();
    for (int s = 128; s > 0; s >>= 1) {
        if (tid < s) {
            red_e[tid] += red_e[tid + s];
            red_d[tid] += red_d[tid + s];
        }
        __syncthreads();
    }
    if (tid == 0) {
        const int bid = blockIdx.y * 16 + blockIdx.x;
        eparts[bid] = red_e[0];
        dparts[bid] = red_d[0];
    }
}

// ---------------------------------------------------------------------------
// finalize: out = mean(t0) - sum(exp)/N^2, reduced in double (512 partials)
// ---------------------------------------------------------------------------
__global__ __launch_bounds__(256) void finalize_kernel(
    const float* __restrict__ eparts, const float* __restrict__ dparts,
    float* __restrict__ out)
{
    __shared__ double se[256];
    __shared__ double sd[256];
    const int t = threadIdx.x;
    se[t] = (double)eparts[t] + (double)eparts[t + 256];
    sd[t] = (double)dparts[t] + (double)dparts[t + 256];
    __syncthreads();
    for (int s = 128; s > 0; s >>= 1) {
        if (t < s) { se[t] += se[t + s]; sd[t] += sd[t + s]; }
        __syncthreads();
    }
    if (t == 0)
        out[0] = (float)(sd[0] / (double)NS - se[0] / ((double)NS * (double)NS));
}

// ---------------------------------------------------------------------------
extern "C" void kernel_launch(void* const* d_in, const int* in_sizes, int n_in,
                              void* d_out, int out_size, void* d_ws, size_t ws_size,
                              hipStream_t stream)
{
    const float* X  = (const float*)d_in[0];
    const float* Y  = (const float*)d_in[1];
    const float* W1 = (const float*)d_in[2];
    const float* b1 = (const float*)d_in[3];
    const float* W2 = (const float*)d_in[4];
    const float* b2 = (const float*)d_in[5];
    float* out = (float*)d_out;

    float* PX     = (float*)d_ws;            // [NS][H]   1 MB
    float* PYB    = PX + NS * H;             // [NS][H]   1 MB
    float* eparts = PYB + NS * H;            // [512]
    float* dparts = eparts + 512;            // [512]

    proj_kernel<<<dim3(H / 64, NS / 32, 2), 256, 0, stream>>>(X, Y, W1, b1, PX, PYB);
    pair_kernel<<<dim3(16, 32), 256, 0, stream>>>(PX, PYB, W2, b2, eparts, dparts);
    finalize_kernel<<<1, 256, 0, stream>>>(eparts, dparts, out);
}